// Round 1
// baseline (189.292 us; speedup 1.0000x reference)
//
#include <hip/hip_runtime.h>

#define N_DATA   128
#define SEG_LEN  131072
#define NPROD    (SEG_LEN - 1)
#define N_MAT    8
#define N_MATP   8
#define N_PROCP  5
#define RGAS     8.314f

#define NCH      64          // chunks per row (== wave size, deliberate)
#define CHUNK    2048        // elements per chunk
#define TPB      256
#define EPT      8           // CHUNK / TPB
#define NBLK     (N_DATA * NCH)   // 8192 chunk-blocks

typedef float nt4 __attribute__((ext_vector_type(4)));  // native vec for nontemporal builtin

// sigma_ss = (base_num*u*Lg + Sigma0*cbd) / (Lg*(u+cbd)),  u = R*Lg + 1e-9
__device__ __forceinline__ float stress_s(float t,
    float alpha1, float L0, float G200, float Sigma0, float A0,
    float inv_tau, float cbd, float base_num, float R) {
  float Lg  = G200 * __expf(alpha1 * __logf(t * (1.0f / 200.0f) + 0.001f)) + L0;
  float u   = R * Lg + 1e-9f;
  float num = base_num * u * Lg + Sigma0 * cbd;
  float den = Lg * (u + cbd);
  float sigma_ss = num * __builtin_amdgcn_rcpf(den);
  return sigma_ss + A0 * __expf(-t * inv_tau);
}

// K0: re-arm the packed {ready|value} words. Workspace is re-poisoned by the
// harness between iterations, so this must run every launch. Kernel (not
// hipMemsetAsync) => unconditionally graph-capture-safe; ~2 us.
__global__ __launch_bounds__(TPB) void k0_init(unsigned long long* __restrict__ cs) {
  cs[blockIdx.x * TPB + threadIdx.x] = 0ull;
}

// Single-pass fused kernel. Each block owns one 2048-element chunk:
//  1. compute products + in-block scan (identical arithmetic to old K2)
//  2. publish chunk total as packed u64 {1<<32 | float_bits}, relaxed
//     agent-scope atomic (single word => no fence needed)
//  3. wave 0 polls the <=63 same-row predecessors' packed words (they all
//     have lower blockIdx; in-order dispatch guarantees forward progress,
//     same assumption as rocPRIM's single-pass scan), shfl-reduces them
//     into the chunk offset
//  4. write final output with the alignment trick (out[i] = K0 + prefix(i-1)
//     -> two aligned float4 nontemporal stores)
// This removes K1's entire 64 MB read pass over x.
__global__ __launch_bounds__(TPB) void k_scan(
    const float* __restrict__ x,
    const float* __restrict__ pc, const float* __restrict__ raw,
    const float* __restrict__ lb, const float* __restrict__ ub,
    const float* __restrict__ sc, const int* __restrict__ mat_idx,
    unsigned long long* __restrict__ cs,
    float* __restrict__ out) {
  __shared__ float pv[13];
  __shared__ float wtot[4];
  __shared__ float choff_s;

  int b   = blockIdx.x;
  int row = b >> 6;
  int ch  = b & (NCH - 1);
  int tid = threadIdx.x;
  int lane = tid & 63, wv = tid >> 6;

  // issue x loads immediately (fly during param compute)
  long rowbase = (long)row * SEG_LEN;
  int  gb = ch * CHUNK + tid * EPT;
  const float* xp = x + rowbase + gb;
  float4 a  = *(const float4*)xp;
  float4 bq = *(const float4*)(xp + 4);
  float  xn = (gb + EPT < SEG_LEN) ? xp[EPT] : 0.0f;

  if (tid < 13) {
    int idx = (tid < 5) ? (N_MAT * N_MATP + row * N_PROCP + tid)
                        : (mat_idx[row] * N_MATP + (tid - 5));
    float s = 1.0f / (1.0f + __expf(-raw[idx]));
    pv[tid] = s * (ub[idx] - lb[idx]) + lb[idx];
  }
  __syncthreads();

  float SigmaC = pv[0], K0 = pv[1], alpha1 = pv[2], L0 = pv[3], G200 = pv[4];
  float Sigma0 = pv[5], BetaD = pv[6], Ea = pv[7], Mfda = pv[8], Di = pv[9];
  float A0 = pv[10], B0 = pv[11], l0 = pv[12];
  float R = pc[row * 4 + 0], T = pc[row * 4 + 1], P = pc[row * 4 + 2];
  float cbd      = BetaD * Di * __expf(-Ea / (RGAS * T));
  float base_num = SigmaC - Mfda * P;
  float inv_tau  = 1.0f / (B0 * l0 + 1e-9f);
  float x_min = sc[0], x_sc = sc[1] - sc[0];
  float y_min = sc[2], inv_yr = 1.0f / (sc[3] - sc[2]);

  float tv[9];
  tv[0] = a.x  * x_sc + x_min; tv[1] = a.y  * x_sc + x_min;
  tv[2] = a.z  * x_sc + x_min; tv[3] = a.w  * x_sc + x_min;
  tv[4] = bq.x * x_sc + x_min; tv[5] = bq.y * x_sc + x_min;
  tv[6] = bq.z * x_sc + x_min; tv[7] = bq.w * x_sc + x_min;
  tv[8] = xn   * x_sc + x_min;

  float pref[EPT];
  float run = 0.0f;
#pragma unroll
  for (int k = 0; k < EPT; k++) {
    float p = 0.0f;
    if (gb + k < NPROD) {
      float s = stress_s(tv[k], alpha1, L0, G200, Sigma0, A0, inv_tau, cbd, base_num, R);
      p = s * (tv[k + 1] - tv[k]);
    }
    run += p;
    pref[k] = run;   // inclusive within thread
  }

  // wave-level inclusive scan of per-thread sums
  float incl = run;
#pragma unroll
  for (int d = 1; d < 64; d <<= 1) {
    float n = __shfl_up(incl, d);
    if (lane >= d) incl += n;
  }
  if (lane == 63) wtot[wv] = incl;
  __syncthreads();

  // publish this chunk's total ASAP (before polling), packed with ready bit
  if (tid == 0) {
    float tot = wtot[0] + wtot[1] + wtot[2] + wtot[3];
    unsigned long long u = (1ull << 32) |
        (unsigned long long)__float_as_uint(tot);
    __hip_atomic_store(cs + b, u, __ATOMIC_RELAXED, __HIP_MEMORY_SCOPE_AGENT);
  }

  // wave 0: lane l waits on same-row predecessor chunk l (l < ch), then
  // reduce the <=63 aggregates into this chunk's exclusive offset
  if (tid < 64) {
    float v = 0.0f;
    int l = tid;
    if (l < ch) {
      const unsigned long long* p = cs + ((row << 6) | l);
      unsigned long long u;
      do {
        u = __hip_atomic_load(p, __ATOMIC_RELAXED, __HIP_MEMORY_SCOPE_AGENT);
      } while ((u >> 32) == 0ull);
      v = __uint_as_float((unsigned)u);
    }
#pragma unroll
    for (int d = 32; d > 0; d >>= 1) v += __shfl_down(v, d);
    if (tid == 0) choff_s = v;
  }
  __syncthreads();

  float choff = choff_s;
  float low = 0.0f;
#pragma unroll
  for (int w = 0; w < 4; w++) low += (w < wv) ? wtot[w] : 0.0f;

  float base = K0 + choff + (incl - run) + low;
  nt4 o0, o1;
  o0.x = (base           - y_min) * inv_yr;
  o0.y = (base + pref[0] - y_min) * inv_yr;
  o0.z = (base + pref[1] - y_min) * inv_yr;
  o0.w = (base + pref[2] - y_min) * inv_yr;
  o1.x = (base + pref[3] - y_min) * inv_yr;
  o1.y = (base + pref[4] - y_min) * inv_yr;
  o1.z = (base + pref[5] - y_min) * inv_yr;
  o1.w = (base + pref[6] - y_min) * inv_yr;
  nt4* op = (nt4*)(out + rowbase + gb);
  __builtin_nontemporal_store(o0, op);       // out never re-read: bypass caches,
  __builtin_nontemporal_store(o1, op + 1);   // preserve x's L2/L3 residency
}

extern "C" void kernel_launch(void* const* d_in, const int* in_sizes, int n_in,
                              void* d_out, int out_size, void* d_ws, size_t ws_size,
                              hipStream_t stream) {
  const float* x_scaled  = (const float*)d_in[0];
  const float* process_c = (const float*)d_in[1];
  const float* raw       = (const float*)d_in[2];
  const float* lb        = (const float*)d_in[3];
  const float* ub        = (const float*)d_in[4];
  const float* sc        = (const float*)d_in[5];
  // d_in[6] = fit_index (unused by the reference computation)
  const int*   mat_idx   = (const int*)d_in[7];
  float* out = (float*)d_out;
  unsigned long long* cs = (unsigned long long*)d_ws;  // 8192 packed {ready|sum}

  k0_init<<<NBLK / TPB, TPB, 0, stream>>>(cs);
  k_scan<<<NBLK, TPB, 0, stream>>>(
      x_scaled, process_c, raw, lb, ub, sc, mat_idx, cs, out);
}